// Round 7
// baseline (299.745 us; speedup 1.0000x reference)
//
#include <hip/hip_runtime.h>

// x (B=64, C=256, T=2048) fp32; conv_weight (256,256,3); beta (1,); b (256,).
// Output spikes (B,C,T) fp32 in {0,1}.
//
// Established across R1-R6: memory throughput here obeys ~latency/outstanding
// (~170-190 cyc per vector-mem instr/CU when issue is bursty); R6's coalesced
// LDS shell (1.00x writes, 0-barrier, wave-local) + 8-seg speculative warmup
// (bit-exact, contraction) reached 91.8 us with a ~30% load duty cycle.
// R7: register prefetch pipeline — next phase's 16 loads issued before this
// phase's compute, so ~16 loads/wave stay in flight continuously.
#define C_DIM 256
#define T_DIM 2048
#define B_DIM 64
#define NROWS (B_DIM * C_DIM)          // 16384
#define SEGS 8
#define SEGL (T_DIM / SEGS)            // 256 emitted timesteps per segment
#define WARM 128                       // speculative warmup steps (bit-exact, r5/r6)
#define PW   64                        // phase window: floats per stream per phase
#define NPH  ((WARM + SEGL) / PW)      // 6 phases
#define WARM_PH (WARM / PW)            // 2 warmup phases
#define SPITCH 68                      // LDS floats per stream: 64 + 4 pad
#define NSTR 64                        // streams per block (= wave size)

__device__ __forceinline__ float sqrn(float v) { return __fmul_rn(v, v); }

// norm[c] = sum of squares of 768 floats in numpy's exact pairwise order
// (768->384->192->96; 96-blocks via 8-accumulator unrolled loop).
// Verified bit-exact (rounds 1-6 absmax 0). DO NOT change the summation tree.
__global__ __launch_bounds__(64) void norm_kernel(const float* __restrict__ w,
                                                  const float* __restrict__ b,
                                                  float* __restrict__ bn,
                                                  float* __restrict__ ninv) {
    const int c = blockIdx.x;
    const int k = threadIdx.x;
    __shared__ float q[8];
    if (k < 8) {
        const float* a = w + c * 768 + k * 96;
        float r0 = sqrn(a[0]), r1 = sqrn(a[1]), r2 = sqrn(a[2]), r3 = sqrn(a[3]);
        float r4 = sqrn(a[4]), r5 = sqrn(a[5]), r6 = sqrn(a[6]), r7 = sqrn(a[7]);
        #pragma unroll
        for (int i = 8; i < 96; i += 8) {
            r0 = __fadd_rn(r0, sqrn(a[i + 0]));
            r1 = __fadd_rn(r1, sqrn(a[i + 1]));
            r2 = __fadd_rn(r2, sqrn(a[i + 2]));
            r3 = __fadd_rn(r3, sqrn(a[i + 3]));
            r4 = __fadd_rn(r4, sqrn(a[i + 4]));
            r5 = __fadd_rn(r5, sqrn(a[i + 5]));
            r6 = __fadd_rn(r6, sqrn(a[i + 6]));
            r7 = __fadd_rn(r7, sqrn(a[i + 7]));
        }
        q[k] = __fadd_rn(__fadd_rn(__fadd_rn(r0, r1), __fadd_rn(r2, r3)),
                         __fadd_rn(__fadd_rn(r4, r5), __fadd_rn(r6, r7)));
    }
    __syncthreads();
    if (k == 0) {
        float s = __fadd_rn(__fadd_rn(__fadd_rn(q[0], q[1]), __fadd_rn(q[2], q[3])),
                            __fadd_rn(__fadd_rn(q[4], q[5]), __fadd_rn(q[6], q[7])));
        bn[c]   = __fmul_rn(b[c], s);
        ninv[c] = 1.0f / __fadd_rn(s, 1e-8f);
    }
}

// One LIF step, bit-exact vs numpy semantics (verified absmax 0, rounds 4-6):
// speculative dual-path update + sign-bit select, no VCC.
__device__ __forceinline__ float step_fast(float xw, float& mem, int& mask,
                                           float bnc, float beta, float nic, float bc) {
    float m0 = __fmul_rn(mem, beta);
    float m1 = __fmul_rn(__fsub_rn(mem, bnc), beta);
    m0 = __fadd_rn(m0, xw);
    m1 = __fadd_rn(m1, xw);
    int mi = (__float_as_int(m1) & mask) | (__float_as_int(m0) & ~mask);
    mem = __int_as_float(mi);
    float p = __fmul_rn(mem, nic);
    float d = __fsub_rn(bc, p);
    mask = __float_as_int(d) >> 31;                 // -1 if spike else 0
    return __int_as_float(mask & 0x3f800000);       // 1.0f or 0.0f
}

#define STEP4_NOSTORE(v)                                                   \
    do {                                                                   \
        float xw0 = __fmul_rn((v).x, omb);                                 \
        float xw1 = __fmul_rn((v).y, omb);                                 \
        float xw2 = __fmul_rn((v).z, omb);                                 \
        float xw3 = __fmul_rn((v).w, omb);                                 \
        (void)step_fast(xw0, mem, mask, bnc, beta, nic, bc);               \
        (void)step_fast(xw1, mem, mask, bnc, beta, nic, bc);               \
        (void)step_fast(xw2, mem, mask, bnc, beta, nic, bc);               \
        (void)step_fast(xw3, mem, mask, bnc, beta, nic, bc);               \
    } while (0)

#define STEP4_STORE(v, o)                                                  \
    do {                                                                   \
        float xw0 = __fmul_rn((v).x, omb);                                 \
        float xw1 = __fmul_rn((v).y, omb);                                 \
        float xw2 = __fmul_rn((v).z, omb);                                 \
        float xw3 = __fmul_rn((v).w, omb);                                 \
        (o).x = step_fast(xw0, mem, mask, bnc, beta, nic, bc);             \
        (o).y = step_fast(xw1, mem, mask, bnc, beta, nic, bc);             \
        (o).z = step_fast(xw2, mem, mask, bnc, beta, nic, bc);             \
        (o).w = step_fast(xw3, mem, mask, bnc, beta, nic, bc);             \
    } while (0)

// lgkm-only wait: cross-lane LDS handoff within a wave (proven r2/r6).
#define WAITCNT_LGKM0  0xC07F

// Block = 1 wave = 64 streams (8 rows x 8 segs). 2048 blocks = 8 waves/CU.
// Stream s: row = blockIdx.x*8 + (s>>3), seg = s&7, local steps [0,384) =
// global t in [seg*256-128, seg*256+256). 6 phases of 64 steps: P 0..1 warmup
// (no output; seg 0 reads clamped addrs then resets), P 2..5 emit.
//
// Pipeline per phase: [ds_write pre->LDS] [lgkm] [issue next phase's 16 loads
// into pre] [compute 64 steps] [emit: spikes->LDS, lgkm, 16 coalesced stores].
// Loads precede the drain stores in program order, so the next phase's
// ds_write only needs vmcnt(16) — stores stay outstanding; loads overlap the
// entire compute+drain stretch (continuous ~16 in flight per wave).
__global__ __launch_bounds__(64) void lif_seg_kernel(const float* __restrict__ x,
                                                     const float* __restrict__ beta_p,
                                                     const float* __restrict__ b,
                                                     const float* __restrict__ bn,
                                                     const float* __restrict__ ninv,
                                                     float* __restrict__ out) {
    __shared__ __align__(16) float lds[NSTR * SPITCH];   // 17408 floats = 17 KB

    const int lane = threadIdx.x;        // = my stream index within block
    const int seg  = lane & 7;
    const int row0 = blockIdx.x * 8;
    const int row  = row0 + (lane >> 3);
    const int c    = row & (C_DIM - 1);

    const float beta = beta_p[0];
    const float omb  = __fsub_rn(1.0f, beta);
    const float bnc  = bn[c];
    const float nic  = ninv[c];
    const float bc   = b[c];

    // Fill/drain lane mapping: instr q covers streams 4q..4q+3; lane i handles
    // stream 4q + (i>>4), float4 index i&15 (256 B per stream per instr).
    const int fh = lane >> 4;            // 0..3
    const int fj = lane & 15;            // 0..15

    float mem = 0.0f;
    int   mask = 0;

    float* my = &lds[lane * SPITCH];
    float4 pre[16];

    // Initial prefetch: phase 0 window for all 64 streams.
    #pragma unroll
    for (int q = 0; q < 16; ++q) {
        const int s    = 4 * q + fh;
        const int srow = row0 + (s >> 3);
        int rel = (s & 7) * SEGL - WARM;              // P=0
        if (rel < 0) rel = 0;                         // clamped (seg 0 warmup, discarded)
        pre[q] = *(const float4*)(x + (size_t)srow * T_DIM + rel + 4 * fj);
    }

    #pragma unroll 1
    for (int P = 0; P < NPH; ++P) {
        // ---- commit prefetched window to LDS (padded layout) ----
        #pragma unroll
        for (int q = 0; q < 16; ++q) {
            const int s = 4 * q + fh;
            *(float4*)(&lds[s * SPITCH + 4 * fj]) = pre[q];
        }
        __builtin_amdgcn_s_waitcnt(WAITCNT_LGKM0);    // cross-lane visibility

        // ---- issue next phase's loads NOW (overlap compute + drain) ----
        if (P + 1 < NPH) {
            #pragma unroll
            for (int q = 0; q < 16; ++q) {
                const int s    = 4 * q + fh;
                const int srow = row0 + (s >> 3);
                int rel = (s & 7) * SEGL - WARM + (P + 1) * PW;
                if (rel < 0) rel = 0;
                pre[q] = *(const float4*)(x + (size_t)srow * T_DIM + rel + 4 * fj);
            }
        }

        if (P < WARM_PH) {
            // ---- warmup phase: 64 steps, no output ----
            #pragma unroll
            for (int g = 0; g < PW / 4; ++g) {
                float4 v = *(const float4*)(my + 4 * g);
                STEP4_NOSTORE(v);
            }
            if (P == WARM_PH - 1) {
                // seg 0 has no predecessor: restore the true initial state.
                if (seg == 0) { mem = 0.0f; mask = 0; }
            }
        } else {
            // ---- emit phase: 64 steps, spikes written back in place ----
            #pragma unroll
            for (int g = 0; g < PW / 4; ++g) {
                float4 v = *(const float4*)(my + 4 * g);
                float4 o;
                STEP4_STORE(v, o);
                *(float4*)(my + 4 * g) = o;
            }
            __builtin_amdgcn_s_waitcnt(WAITCNT_LGKM0);   // spikes visible to drain lanes

            // ---- drain: 16 coalesced stores (exactly tiles out, 1.00x) ----
            #pragma unroll
            for (int q = 0; q < 16; ++q) {
                const int s    = 4 * q + fh;
                const int srow = row0 + (s >> 3);
                const int rel  = (s & 7) * SEGL - WARM + P * PW;   // >= 0 for P >= 2
                float4 v = *(const float4*)(&lds[s * SPITCH + 4 * fj]);
                *(float4*)(out + (size_t)srow * T_DIM + rel + 4 * fj) = v;
            }
        }
    }
}

extern "C" void kernel_launch(void* const* d_in, const int* in_sizes, int n_in,
                              void* d_out, int out_size, void* d_ws, size_t ws_size,
                              hipStream_t stream) {
    const float* x    = (const float*)d_in[0];
    const float* w    = (const float*)d_in[1];
    const float* beta = (const float*)d_in[2];
    const float* b    = (const float*)d_in[3];
    float* out  = (float*)d_out;
    float* bn   = (float*)d_ws;          // 256 floats
    float* ninv = bn + C_DIM;            // 256 floats

    norm_kernel<<<C_DIM, 64, 0, stream>>>(w, b, bn, ninv);
    lif_seg_kernel<<<(NROWS * SEGS) / NSTR, NSTR, 0, stream>>>(x, beta, b, bn, ninv, out);
}

// Round 8
// 298.396 us; speedup vs baseline: 1.0045x; 1.0045x over previous
//
#include <hip/hip_runtime.h>

// x (B=64, C=256, T=2048) fp32; conv_weight (256,256,3); beta (1,); b (256,).
// Output spikes (B,C,T) fp32 in {0,1}.
//
// Established R1-R7: memory throughput ~ latency/outstanding; R6 shell
// (coalesced LDS staging, 1.00x writes, wave-local, 8-seg bit-exact warmup)
// = 91.8 us at ~30% load duty. R7's register prefetch pipeline raised HBM BW
// to 3.8 TB/s but the compiler SPILLED pre[16] (VGPR_Count stuck at 68 under
// default launch bounds) -> +196MB scratch writes +167MB scratch reads.
// R8: identical pipeline, __launch_bounds__(64,2) -> VGPR cap 256, no spill.
#define C_DIM 256
#define T_DIM 2048
#define B_DIM 64
#define NROWS (B_DIM * C_DIM)          // 16384
#define SEGS 8
#define SEGL (T_DIM / SEGS)            // 256 emitted timesteps per segment
#define WARM 128                       // speculative warmup steps (bit-exact, r5/r6)
#define PW   64                        // phase window: floats per stream per phase
#define NPH  ((WARM + SEGL) / PW)      // 6 phases
#define WARM_PH (WARM / PW)            // 2 warmup phases
#define SPITCH 68                      // LDS floats per stream: 64 + 4 pad
#define NSTR 64                        // streams per block (= wave size)

__device__ __forceinline__ float sqrn(float v) { return __fmul_rn(v, v); }

// norm[c] = sum of squares of 768 floats in numpy's exact pairwise order
// (768->384->192->96; 96-blocks via 8-accumulator unrolled loop).
// Verified bit-exact (rounds 1-7 absmax 0). DO NOT change the summation tree.
__global__ __launch_bounds__(64) void norm_kernel(const float* __restrict__ w,
                                                  const float* __restrict__ b,
                                                  float* __restrict__ bn,
                                                  float* __restrict__ ninv) {
    const int c = blockIdx.x;
    const int k = threadIdx.x;
    __shared__ float q[8];
    if (k < 8) {
        const float* a = w + c * 768 + k * 96;
        float r0 = sqrn(a[0]), r1 = sqrn(a[1]), r2 = sqrn(a[2]), r3 = sqrn(a[3]);
        float r4 = sqrn(a[4]), r5 = sqrn(a[5]), r6 = sqrn(a[6]), r7 = sqrn(a[7]);
        #pragma unroll
        for (int i = 8; i < 96; i += 8) {
            r0 = __fadd_rn(r0, sqrn(a[i + 0]));
            r1 = __fadd_rn(r1, sqrn(a[i + 1]));
            r2 = __fadd_rn(r2, sqrn(a[i + 2]));
            r3 = __fadd_rn(r3, sqrn(a[i + 3]));
            r4 = __fadd_rn(r4, sqrn(a[i + 4]));
            r5 = __fadd_rn(r5, sqrn(a[i + 5]));
            r6 = __fadd_rn(r6, sqrn(a[i + 6]));
            r7 = __fadd_rn(r7, sqrn(a[i + 7]));
        }
        q[k] = __fadd_rn(__fadd_rn(__fadd_rn(r0, r1), __fadd_rn(r2, r3)),
                         __fadd_rn(__fadd_rn(r4, r5), __fadd_rn(r6, r7)));
    }
    __syncthreads();
    if (k == 0) {
        float s = __fadd_rn(__fadd_rn(__fadd_rn(q[0], q[1]), __fadd_rn(q[2], q[3])),
                            __fadd_rn(__fadd_rn(q[4], q[5]), __fadd_rn(q[6], q[7])));
        bn[c]   = __fmul_rn(b[c], s);
        ninv[c] = 1.0f / __fadd_rn(s, 1e-8f);
    }
}

// One LIF step, bit-exact vs numpy semantics (verified absmax 0, rounds 4-7):
// speculative dual-path update + sign-bit select, no VCC.
__device__ __forceinline__ float step_fast(float xw, float& mem, int& mask,
                                           float bnc, float beta, float nic, float bc) {
    float m0 = __fmul_rn(mem, beta);
    float m1 = __fmul_rn(__fsub_rn(mem, bnc), beta);
    m0 = __fadd_rn(m0, xw);
    m1 = __fadd_rn(m1, xw);
    int mi = (__float_as_int(m1) & mask) | (__float_as_int(m0) & ~mask);
    mem = __int_as_float(mi);
    float p = __fmul_rn(mem, nic);
    float d = __fsub_rn(bc, p);
    mask = __float_as_int(d) >> 31;                 // -1 if spike else 0
    return __int_as_float(mask & 0x3f800000);       // 1.0f or 0.0f
}

#define STEP4_NOSTORE(v)                                                   \
    do {                                                                   \
        float xw0 = __fmul_rn((v).x, omb);                                 \
        float xw1 = __fmul_rn((v).y, omb);                                 \
        float xw2 = __fmul_rn((v).z, omb);                                 \
        float xw3 = __fmul_rn((v).w, omb);                                 \
        (void)step_fast(xw0, mem, mask, bnc, beta, nic, bc);               \
        (void)step_fast(xw1, mem, mask, bnc, beta, nic, bc);               \
        (void)step_fast(xw2, mem, mask, bnc, beta, nic, bc);               \
        (void)step_fast(xw3, mem, mask, bnc, beta, nic, bc);               \
    } while (0)

#define STEP4_STORE(v, o)                                                  \
    do {                                                                   \
        float xw0 = __fmul_rn((v).x, omb);                                 \
        float xw1 = __fmul_rn((v).y, omb);                                 \
        float xw2 = __fmul_rn((v).z, omb);                                 \
        float xw3 = __fmul_rn((v).w, omb);                                 \
        (o).x = step_fast(xw0, mem, mask, bnc, beta, nic, bc);             \
        (o).y = step_fast(xw1, mem, mask, bnc, beta, nic, bc);             \
        (o).z = step_fast(xw2, mem, mask, bnc, beta, nic, bc);             \
        (o).w = step_fast(xw3, mem, mask, bnc, beta, nic, bc);             \
    } while (0)

// lgkm-only wait: cross-lane LDS handoff within a wave (proven r2/r6).
#define WAITCNT_LGKM0  0xC07F

// Block = 1 wave = 64 streams (8 rows x 8 segs). 2048 blocks = 8 waves/CU.
// Stream s: row = blockIdx.x*8 + (s>>3), seg = s&7, local steps [0,384) =
// global t in [seg*256-128, seg*256+256). 6 phases of 64 steps: P 0..1 warmup
// (no output; seg 0 reads clamped addrs then resets), P 2..5 emit.
//
// Pipeline per phase: [ds_write pre->LDS] [lgkm] [issue next phase's 16 loads
// into pre] [compute 64 steps] [emit: spikes->LDS, lgkm, 16 coalesced stores].
// Loads overlap the entire compute+drain stretch (~16 in flight per wave,
// continuously). __launch_bounds__(64,2): VGPR cap 256 so pre[16] (64 VGPRs)
// stays in registers — R7 proved the default bounds spill it to scratch
// (+360MB HBM traffic). 2 waves/EU * 4 EU = 8 blocks/CU = our launch envelope.
__global__ __launch_bounds__(64, 2) void lif_seg_kernel(const float* __restrict__ x,
                                                        const float* __restrict__ beta_p,
                                                        const float* __restrict__ b,
                                                        const float* __restrict__ bn,
                                                        const float* __restrict__ ninv,
                                                        float* __restrict__ out) {
    __shared__ __align__(16) float lds[NSTR * SPITCH];   // 17408 floats = 17 KB

    const int lane = threadIdx.x;        // = my stream index within block
    const int seg  = lane & 7;
    const int row0 = blockIdx.x * 8;
    const int row  = row0 + (lane >> 3);
    const int c    = row & (C_DIM - 1);

    const float beta = beta_p[0];
    const float omb  = __fsub_rn(1.0f, beta);
    const float bnc  = bn[c];
    const float nic  = ninv[c];
    const float bc   = b[c];

    // Fill/drain lane mapping: instr q covers streams 4q..4q+3; lane i handles
    // stream 4q + (i>>4), float4 index i&15 (256 B per stream per instr).
    const int fh = lane >> 4;            // 0..3
    const int fj = lane & 15;            // 0..15

    float mem = 0.0f;
    int   mask = 0;

    float* my = &lds[lane * SPITCH];
    float4 pre[16];

    // Initial prefetch: phase 0 window for all 64 streams.
    #pragma unroll
    for (int q = 0; q < 16; ++q) {
        const int s    = 4 * q + fh;
        const int srow = row0 + (s >> 3);
        int rel = (s & 7) * SEGL - WARM;              // P=0
        if (rel < 0) rel = 0;                         // clamped (seg 0 warmup, discarded)
        pre[q] = *(const float4*)(x + (size_t)srow * T_DIM + rel + 4 * fj);
    }

    #pragma unroll 1
    for (int P = 0; P < NPH; ++P) {
        // ---- commit prefetched window to LDS (padded layout) ----
        #pragma unroll
        for (int q = 0; q < 16; ++q) {
            const int s = 4 * q + fh;
            *(float4*)(&lds[s * SPITCH + 4 * fj]) = pre[q];
        }
        __builtin_amdgcn_s_waitcnt(WAITCNT_LGKM0);    // cross-lane visibility

        // ---- issue next phase's loads NOW (overlap compute + drain) ----
        if (P + 1 < NPH) {
            #pragma unroll
            for (int q = 0; q < 16; ++q) {
                const int s    = 4 * q + fh;
                const int srow = row0 + (s >> 3);
                int rel = (s & 7) * SEGL - WARM + (P + 1) * PW;
                if (rel < 0) rel = 0;
                pre[q] = *(const float4*)(x + (size_t)srow * T_DIM + rel + 4 * fj);
            }
        }

        if (P < WARM_PH) {
            // ---- warmup phase: 64 steps, no output ----
            #pragma unroll
            for (int g = 0; g < PW / 4; ++g) {
                float4 v = *(const float4*)(my + 4 * g);
                STEP4_NOSTORE(v);
            }
            if (P == WARM_PH - 1) {
                // seg 0 has no predecessor: restore the true initial state.
                if (seg == 0) { mem = 0.0f; mask = 0; }
            }
        } else {
            // ---- emit phase: 64 steps, spikes written back in place ----
            #pragma unroll
            for (int g = 0; g < PW / 4; ++g) {
                float4 v = *(const float4*)(my + 4 * g);
                float4 o;
                STEP4_STORE(v, o);
                *(float4*)(my + 4 * g) = o;
            }
            __builtin_amdgcn_s_waitcnt(WAITCNT_LGKM0);   // spikes visible to drain lanes

            // ---- drain: 16 coalesced stores (exactly tiles out, 1.00x) ----
            #pragma unroll
            for (int q = 0; q < 16; ++q) {
                const int s    = 4 * q + fh;
                const int srow = row0 + (s >> 3);
                const int rel  = (s & 7) * SEGL - WARM + P * PW;   // >= 0 for P >= 2
                float4 v = *(const float4*)(&lds[s * SPITCH + 4 * fj]);
                *(float4*)(out + (size_t)srow * T_DIM + rel + 4 * fj) = v;
            }
        }
    }
}

extern "C" void kernel_launch(void* const* d_in, const int* in_sizes, int n_in,
                              void* d_out, int out_size, void* d_ws, size_t ws_size,
                              hipStream_t stream) {
    const float* x    = (const float*)d_in[0];
    const float* w    = (const float*)d_in[1];
    const float* beta = (const float*)d_in[2];
    const float* b    = (const float*)d_in[3];
    float* out  = (float*)d_out;
    float* bn   = (float*)d_ws;          // 256 floats
    float* ninv = bn + C_DIM;            // 256 floats

    norm_kernel<<<C_DIM, 64, 0, stream>>>(w, b, bn, ninv);
    lif_seg_kernel<<<(NROWS * SEGS) / NSTR, NSTR, 0, stream>>>(x, beta, b, bn, ninv, out);
}

// Round 9
// 256.640 us; speedup vs baseline: 1.1680x; 1.1627x over previous
//
#include <hip/hip_runtime.h>

// x (B=64, C=256, T=2048) fp32; conv_weight (256,256,3); beta (1,); b (256,).
// Output spikes (B,C,T) fp32 in {0,1}.
//
// R1-R8 established: (a) latency/occupancy-bound, need ~8 waves/CU (R6);
// (b) loads must stay in flight across the compute phase (R7 raised BW to
// 3.8 TB/s); (c) holding the prefetch in VGPRs spills — the allocator pins a
// ~64-VGPR budget for 64-thread blocks and launch_bounds(64,2) does NOT relax
// it (R8: VGPR stuck at 68, 327MB scratch traffic). R9: prefetch via
// global->LDS DMA (zero VGPRs, R2-proven semantics), double-buffered 8KB
// windows, XOR-rotation LDS swizzle instead of padding (DMA needs contiguous
// LDS destinations; rotation keeps compute reads at the b128 8-lanes/quad
// floor while the DMA's per-lane GLOBAL addresses absorb the permutation).
#define C_DIM 256
#define T_DIM 2048
#define B_DIM 64
#define NROWS (B_DIM * C_DIM)          // 16384
#define SEGS 8
#define SEGL (T_DIM / SEGS)            // 256 emitted timesteps per segment
#define WARM 128                       // speculative warmup steps (bit-exact, r5-r8)
#define PW   32                        // phase window: floats per stream per phase
#define NPH  ((WARM + SEGL) / PW)      // 12 phases
#define WARM_PH (WARM / PW)            // 4 warmup phases
#define NSTR 64                        // streams per block (= wave size)

__device__ __forceinline__ float sqrn(float v) { return __fmul_rn(v, v); }

// norm[c] = sum of squares of 768 floats in numpy's exact pairwise order
// (768->384->192->96; 96-blocks via 8-accumulator unrolled loop).
// Verified bit-exact (rounds 1-8 absmax 0). DO NOT change the summation tree.
__global__ __launch_bounds__(64) void norm_kernel(const float* __restrict__ w,
                                                  const float* __restrict__ b,
                                                  float* __restrict__ bn,
                                                  float* __restrict__ ninv) {
    const int c = blockIdx.x;
    const int k = threadIdx.x;
    __shared__ float q[8];
    if (k < 8) {
        const float* a = w + c * 768 + k * 96;
        float r0 = sqrn(a[0]), r1 = sqrn(a[1]), r2 = sqrn(a[2]), r3 = sqrn(a[3]);
        float r4 = sqrn(a[4]), r5 = sqrn(a[5]), r6 = sqrn(a[6]), r7 = sqrn(a[7]);
        #pragma unroll
        for (int i = 8; i < 96; i += 8) {
            r0 = __fadd_rn(r0, sqrn(a[i + 0]));
            r1 = __fadd_rn(r1, sqrn(a[i + 1]));
            r2 = __fadd_rn(r2, sqrn(a[i + 2]));
            r3 = __fadd_rn(r3, sqrn(a[i + 3]));
            r4 = __fadd_rn(r4, sqrn(a[i + 4]));
            r5 = __fadd_rn(r5, sqrn(a[i + 5]));
            r6 = __fadd_rn(r6, sqrn(a[i + 6]));
            r7 = __fadd_rn(r7, sqrn(a[i + 7]));
        }
        q[k] = __fadd_rn(__fadd_rn(__fadd_rn(r0, r1), __fadd_rn(r2, r3)),
                         __fadd_rn(__fadd_rn(r4, r5), __fadd_rn(r6, r7)));
    }
    __syncthreads();
    if (k == 0) {
        float s = __fadd_rn(__fadd_rn(__fadd_rn(q[0], q[1]), __fadd_rn(q[2], q[3])),
                            __fadd_rn(__fadd_rn(q[4], q[5]), __fadd_rn(q[6], q[7])));
        bn[c]   = __fmul_rn(b[c], s);
        ninv[c] = 1.0f / __fadd_rn(s, 1e-8f);
    }
}

// One LIF step, bit-exact vs numpy semantics (verified absmax 0, rounds 4-8):
// speculative dual-path update + sign-bit select, no VCC.
__device__ __forceinline__ float step_fast(float xw, float& mem, int& mask,
                                           float bnc, float beta, float nic, float bc) {
    float m0 = __fmul_rn(mem, beta);
    float m1 = __fmul_rn(__fsub_rn(mem, bnc), beta);
    m0 = __fadd_rn(m0, xw);
    m1 = __fadd_rn(m1, xw);
    int mi = (__float_as_int(m1) & mask) | (__float_as_int(m0) & ~mask);
    mem = __int_as_float(mi);
    float p = __fmul_rn(mem, nic);
    float d = __fsub_rn(bc, p);
    mask = __float_as_int(d) >> 31;                 // -1 if spike else 0
    return __int_as_float(mask & 0x3f800000);       // 1.0f or 0.0f
}

#define STEP4_NOSTORE(v)                                                   \
    do {                                                                   \
        float xw0 = __fmul_rn((v).x, omb);                                 \
        float xw1 = __fmul_rn((v).y, omb);                                 \
        float xw2 = __fmul_rn((v).z, omb);                                 \
        float xw3 = __fmul_rn((v).w, omb);                                 \
        (void)step_fast(xw0, mem, mask, bnc, beta, nic, bc);               \
        (void)step_fast(xw1, mem, mask, bnc, beta, nic, bc);               \
        (void)step_fast(xw2, mem, mask, bnc, beta, nic, bc);               \
        (void)step_fast(xw3, mem, mask, bnc, beta, nic, bc);               \
    } while (0)

#define STEP4_STORE(v, o)                                                  \
    do {                                                                   \
        float xw0 = __fmul_rn((v).x, omb);                                 \
        float xw1 = __fmul_rn((v).y, omb);                                 \
        float xw2 = __fmul_rn((v).z, omb);                                 \
        float xw3 = __fmul_rn((v).w, omb);                                 \
        (o).x = step_fast(xw0, mem, mask, bnc, beta, nic, bc);             \
        (o).y = step_fast(xw1, mem, mask, bnc, beta, nic, bc);             \
        (o).z = step_fast(xw2, mem, mask, bnc, beta, nic, bc);             \
        (o).w = step_fast(xw3, mem, mask, bnc, beta, nic, bc);             \
    } while (0)

// s_waitcnt immediates (gfx9: vm[3:0]|exp[6:4]|lgkm[11:8]|vm[5:4]@[15:14])
#define WAITCNT_VM0    0x0F70  // vmcnt(0),  lgkm no-wait
#define WAITCNT_VM8    0x0F78  // vmcnt(8),  lgkm no-wait (8 newest = drain stores)
#define WAITCNT_LGKM0  0xC07F  // lgkmcnt(0), vm no-wait

#define LDS_PTR(p) ((__attribute__((address_space(3))) void*)(p))
#define GLB_PTR(p) ((const __attribute__((address_space(1))) void*)(p))

// Block = 1 wave = 64 streams (8 rows x 8 segs); thread lane owns stream lane:
// row = row0 + (lane>>3), seg = lane&7, local window [seg*256-128, seg*256+256).
// 12 phases x 32 steps: P 0..3 warmup (seg 0 reads clamped, then resets to the
// true init), P 4..11 emit.
//
// LDS layout (per 8KB buffer): stream s occupies floats [s*32, s*32+32);
// granule g (4 floats) sits at position (g+s)&7 -> compute/emit b128 quad index
// = (g+s)&7, even 8 lanes/quad (the b128 floor). DMA instr q fills the 1KB
// [q*256, q*256+256) contiguously (HW: uniform base + lane*16B): lane l holds
// row row0+q, seg l>>3, granule ((l&7)-(l>>3))&7 — the rotation is absorbed by
// the per-lane GLOBAL address, lines stay fully covered.
//
// Pipeline per phase: [wait vmcnt(8 if P>=5 else 0): DMA(P) landed, prior
// drain stores stay in flight] [issue 8 DMA for P+1 -> other buffer]
// [compute 32 steps] [emit: spikes in place, lgkm, 8 coalesced stores].
// Zero VGPR prefetch cost -> fits the allocator's 64-VGPR budget, no scratch.
__global__ __launch_bounds__(64) void lif_seg_kernel(const float* __restrict__ x,
                                                     const float* __restrict__ beta_p,
                                                     const float* __restrict__ b,
                                                     const float* __restrict__ bn,
                                                     const float* __restrict__ ninv,
                                                     float* __restrict__ out) {
    __shared__ __align__(16) float lds[2][NSTR * PW];   // 2 x 8 KB

    const int lane = threadIdx.x;        // = my stream index within block
    const int seg  = lane & 7;
    const int row0 = blockIdx.x * 8;
    const int row  = row0 + (lane >> 3);
    const int c    = row & (C_DIM - 1);

    const float beta = beta_p[0];
    const float omb  = __fsub_rn(1.0f, beta);
    const float bnc  = bn[c];
    const float nic  = ninv[c];
    const float bc   = b[c];

    // Fill/drain lane constants: instr q covers row row0+q, all 8 segments;
    // lane l handles segment l>>3, granule ((l&7)-(l>>3))&7.
    const int fseg = lane >> 3;
    const int fg   = ((lane & 7) - fseg) & 7;

    float mem = 0.0f;
    int   mask = 0;

    // Initial DMA: phase 0 window into buffer 0.
    {
        int rel = fseg * SEGL - WARM;                // P=0
        if (rel < 0) rel = 0;                        // seg-0 warmup clamp (discarded)
        #pragma unroll
        for (int q = 0; q < 8; ++q) {
            const float* g = x + (size_t)(row0 + q) * T_DIM + rel + 4 * fg;
            __builtin_amdgcn_global_load_lds(GLB_PTR(g), LDS_PTR(&lds[0][q * 256]), 16, 0, 0);
        }
    }

    #pragma unroll 1
    for (int P = 0; P < NPH; ++P) {
        // DMA(P) was issued a full phase ago; the 8 newest outstanding vm-ops
        // (P>=5) are the previous drain stores — leave them in flight.
        if (P >= 5) __builtin_amdgcn_s_waitcnt(WAITCNT_VM8);
        else        __builtin_amdgcn_s_waitcnt(WAITCNT_VM0);

        // Issue next phase's DMA into the other buffer (after the wait!).
        if (P + 1 < NPH) {
            int relb = fseg * SEGL - WARM + (P + 1) * PW;
            if (relb < 0) relb = 0;
            float* dbuf = &lds[(P + 1) & 1][0];
            #pragma unroll
            for (int q = 0; q < 8; ++q) {
                const float* g = x + (size_t)(row0 + q) * T_DIM + relb + 4 * fg;
                __builtin_amdgcn_global_load_lds(GLB_PTR(g), LDS_PTR(dbuf + q * 256), 16, 0, 0);
            }
        }

        float* buf = &lds[P & 1][0];
        float* my  = buf + lane * PW;

        if (P < WARM_PH) {
            // ---- warmup: 32 steps, no output ----
            #pragma unroll
            for (int g = 0; g < PW / 4; ++g) {
                float4 v = *(const float4*)(my + 4 * ((g + seg) & 7));
                STEP4_NOSTORE(v);
            }
            // seg 0 has no predecessor: restore the true initial state.
            if (P == WARM_PH - 1 && seg == 0) { mem = 0.0f; mask = 0; }
        } else {
            // ---- emit: 32 steps, spikes written back in place ----
            #pragma unroll
            for (int g = 0; g < PW / 4; ++g) {
                float* p = my + 4 * ((g + seg) & 7);
                float4 v = *(const float4*)p;
                float4 o;
                STEP4_STORE(v, o);
                *(float4*)p = o;
            }
            __builtin_amdgcn_s_waitcnt(WAITCNT_LGKM0);   // cross-lane visibility

            // ---- drain: 8 coalesced 1KB stores (inverse granule permutation
            // on the global side; every 64B line fully covered) ----
            const size_t ob = (size_t)fseg * SEGL + (size_t)(P * PW - WARM) + 4 * fg;
            #pragma unroll
            for (int q = 0; q < 8; ++q) {
                float4 v = *(const float4*)(buf + q * 256 + 4 * lane);
                *(float4*)(out + (size_t)(row0 + q) * T_DIM + ob) = v;
            }
        }
    }
}

extern "C" void kernel_launch(void* const* d_in, const int* in_sizes, int n_in,
                              void* d_out, int out_size, void* d_ws, size_t ws_size,
                              hipStream_t stream) {
    const float* x    = (const float*)d_in[0];
    const float* w    = (const float*)d_in[1];
    const float* beta = (const float*)d_in[2];
    const float* b    = (const float*)d_in[3];
    float* out  = (float*)d_out;
    float* bn   = (float*)d_ws;          // 256 floats
    float* ninv = bn + C_DIM;            // 256 floats

    norm_kernel<<<C_DIM, 64, 0, stream>>>(w, b, bn, ninv);
    lif_seg_kernel<<<(NROWS * SEGS) / NSTR, NSTR, 0, stream>>>(x, beta, b, bn, ninv, out);
}